// Round 11
// baseline (120.012 us; speedup 1.0000x reference)
//
#include <hip/hip_runtime.h>
#include <hip/hip_fp16.h>

// RNN-T loss forward: B=8, T=128, U=100, V=1024, BLANK=0.
// out = mean_b of -( alpha[tl-2, ul] + blank_lp[tl-2, ul] )
//
// lse_kernel: log-softmax over V; store the two needed log-probs fp16 into
//   LINEAR DENSE staging (full-line coalesced writebacks — no scattered
//   partial-line flush flood at the kernel boundary).
// dp_kernel: one block (9 waves) per batch. Waves 1..8 gather-transpose the
//   linear staging into diagonal-major LDS (region of 29 diagonals each,
//   independent 2B gathers, TLP-hidden) and release an LDS flag; wave 0 runs
//   the 232-step anti-diagonal chain from LDS (round-10-proven code).

#define NEGV (-1e30f)

constexpr int Bb = 8;
constexpr int Tt = 128;
constexpr int Uu = 100;
constexpr int Vv = 1024;
constexpr int UP1 = Uu + 1;
constexpr int BLK_N = Tt * UP1;   // 12928 blank entries per batch
constexpr int EMT_N = Tt * Uu;    // 12800 emit entries per batch
constexpr int DPAD  = 104;        // LDS diagonal row pitch (halves)
constexpr int LROWS = 233;        // LDS rows d = 0..232
constexpr int REG   = 29;         // diagonals per copy region
constexpr int NREG  = 8;          // 8 * 29 = 232 diagonals

__device__ __forceinline__ float laddexp(float x, float y) {
    float m = fmaxf(x, y);
    float d = fabsf(x - y);
    return m + __logf(1.0f + __expf(-d));
}

// lane l receives lane l-1's value; lane 0 -> 0
__device__ __forceinline__ float wave_shr1(float x) {
    return __builtin_bit_cast(float, __builtin_amdgcn_update_dpp(
        0, __builtin_bit_cast(int, x), 0x138, 0xf, 0xf, true));
}

__device__ __forceinline__ float readlane_f(float x, int lane) {
    return __builtin_bit_cast(float,
        __builtin_amdgcn_readlane(__builtin_bit_cast(int, x), lane));
}

// Kernel 1: per (b,t,u) row of V=1024 logits compute lse; store fp16 linear:
//   blankH[wid] = blank_lp[b][t][u],  emitH[b*12800 + t*100 + u] = emit_lp.
__global__ __launch_bounds__(256) void lse_kernel(
        const float* __restrict__ logits,
        const int*   __restrict__ targets,
        __half* __restrict__ blankH,
        __half* __restrict__ emitH) {
    const int wid  = blockIdx.x * 4 + (threadIdx.x >> 6);   // row index
    const int lane = threadIdx.x & 63;
    const int b   = wid / BLK_N;
    const int rem = wid - b * BLK_N;
    const int t   = rem / UP1;
    const int u   = rem - t * UP1;

    const float* row = logits + (size_t)wid * Vv;
    const float4* r4 = (const float4*)row;
    float4 x0 = r4[lane];
    float4 x1 = r4[lane + 64];
    float4 x2 = r4[lane + 128];
    float4 x3 = r4[lane + 192];

    float m = fmaxf(fmaxf(fmaxf(x0.x, x0.y), fmaxf(x0.z, x0.w)),
                    fmaxf(fmaxf(x1.x, x1.y), fmaxf(x1.z, x1.w)));
    m = fmaxf(m, fmaxf(fmaxf(fmaxf(x2.x, x2.y), fmaxf(x2.z, x2.w)),
                       fmaxf(fmaxf(x3.x, x3.y), fmaxf(x3.z, x3.w))));
    #pragma unroll
    for (int d = 32; d > 0; d >>= 1) m = fmaxf(m, __shfl_xor(m, d, 64));

    float s = __expf(x0.x - m) + __expf(x0.y - m) + __expf(x0.z - m) + __expf(x0.w - m)
            + __expf(x1.x - m) + __expf(x1.y - m) + __expf(x1.z - m) + __expf(x1.w - m)
            + __expf(x2.x - m) + __expf(x2.y - m) + __expf(x2.z - m) + __expf(x2.w - m)
            + __expf(x3.x - m) + __expf(x3.y - m) + __expf(x3.z - m) + __expf(x3.w - m);
    #pragma unroll
    for (int d = 32; d > 0; d >>= 1) s += __shfl_xor(s, d, 64);

    float lse = m + __logf(s);

    if (lane == 0) {
        blankH[wid] = __float2half(x0.x - lse);          // row[0] = BLANK
        if (u < Uu) {
            int tgt = targets[b * Uu + u];
            emitH[b * EMT_N + t * Uu + u] = __float2half(row[tgt] - lse);
        }
    }
}

// Kernel 2: one 576-thread block (9 waves) per batch element.
__global__ __launch_bounds__(576) void dp_kernel(
        const __half* __restrict__ blankH,
        const __half* __restrict__ emitH,
        const int*    __restrict__ logit_lengths,
        const int*    __restrict__ target_lengths,
        float* __restrict__ nll) {
    const int b    = blockIdx.x;
    const int tid  = threadIdx.x;
    const int wvi  = tid >> 6;          // 0 = consumer, 1..8 = copy waves
    const int lane = tid & 63;

    // diagonal-major LDS:  lB[d][u] = blank[d-1-u][u],  lE[d][u] = emit[d-u][u-1]
    __shared__ __half lB[LROWS][DPAD];
    __shared__ __half lE[LROWS][DPAD];
    __shared__ int sflag[NREG];

    if (tid < NREG) sflag[tid] = 0;
    __syncthreads();

    if (wvi >= 1) {
        // -------- copy wave: gather-transpose region w (29 diagonal rows) --
        const int w = wvi - 1;
        const int dbase = 1 + REG * w;
        const __half* bSrc = blankH + (size_t)b * BLK_N;
        const __half* eSrc = emitH  + (size_t)b * EMT_N;
        for (int j = lane; j < REG * DPAD; j += 64) {
            const int r = j / DPAD;
            const int u = j - r * DPAD;
            const int d = dbase + r;
            const int tb = d - 1 - u;                    // blank source t
            __half hb = (tb >= 0 && tb < Tt && u <= Uu)
                      ? bSrc[tb * UP1 + u] : __half(0.0f);
            lB[d][u] = hb;
            const int te = d - u;                        // emit source t
            __half he = (u >= 1 && u <= Uu && te >= 0 && te < Tt)
                      ? eSrc[te * Uu + (u - 1)] : __half(0.0f);
            lE[d][u] = he;
        }
        __hip_atomic_store(&sflag[w], 1, __ATOMIC_RELEASE,
                           __HIP_MEMORY_SCOPE_WORKGROUP);
        return;
    }

    // -------- consumer wave: 232-step anti-diagonal chain from LDS --------
    const int tl = logit_lengths[b];
    const int ul = target_lengths[b];
    const int t_idx = tl - 2;           // reference reads alpha[tl-2][ul]
    const int dcap  = t_idx + ul;       // diagonal of the readout cell

    const int u0 = lane * 2, u1 = u0 + 1;
    float aP0 = (lane == 0) ? 0.0f : NEGV;   // alpha diag 0: only (0,0)=0
    float aP1 = NEGV;
    float cap = (dcap == 0) ? 0.0f : NEGV;

    for (int w = 0; w < NREG; ++w) {
        while (__hip_atomic_load(&sflag[w], __ATOMIC_ACQUIRE,
                                 __HIP_MEMORY_SCOPE_WORKGROUP) == 0)
            __builtin_amdgcn_s_sleep(1);
        __builtin_amdgcn_sched_barrier(0);

        const int dbase = 1 + REG * w;
        for (int j = 0; j < REG; ++j) {
            const int dv = dbase + j;
            const __half2 hB = *(const __half2*)&lB[dv][u0];
            const __half2 hE = *(const __half2*)&lE[dv][u0];
            const float2 Bf = __half22float2(hB);
            const float2 Ef = __half22float2(hE);
            float sh  = wave_shr1(aP1);
            float t1b = (u1 < dv) ? aP1 + Bf.y : NEGV;
            float t1e = aP0 + Ef.y;
            float t0b = (u0 < dv) ? aP0 + Bf.x : NEGV;
            float t0e = (lane >= 1) ? sh + Ef.x : NEGV;
            float n1 = laddexp(t1b, t1e);
            float n0 = laddexp(t0b, t0e);
            aP0 = n0; aP1 = n1;
            if (dv == dcap) {
                float w0 = readlane_f(n0, ul >> 1);
                float w1 = readlane_f(n1, ul >> 1);
                cap = (ul & 1) ? w1 : w0;
            }
        }
    }

    if (lane == 0) {
        // final blank term: diagonal row dcap+1 (<= 227), slot ul
        float blk = __half2float(lB[dcap + 1][ul]);
        nll[b] = -(cap + blk);
    }
}

__global__ void mean_kernel(const float* __restrict__ nll, float* __restrict__ out) {
    if (threadIdx.x == 0 && blockIdx.x == 0) {
        float s = 0.0f;
        for (int i = 0; i < Bb; ++i) s += nll[i];
        out[0] = s / (float)Bb;
    }
}

extern "C" void kernel_launch(void* const* d_in, const int* in_sizes, int n_in,
                              void* d_out, int out_size, void* d_ws, size_t ws_size,
                              hipStream_t stream) {
    const float* logits         = (const float*)d_in[0];
    const int*   targets        = (const int*)d_in[1];
    const int*   logit_lengths  = (const int*)d_in[2];
    const int*   target_lengths = (const int*)d_in[3];
    float* out = (float*)d_out;

    __half* blankH = (__half*)d_ws;                      // 8*12928 halves
    __half* emitH  = blankH + (size_t)Bb * BLK_N;        // 8*12800 halves
    float*  nll    = (float*)(emitH + (size_t)Bb * EMT_N);   // 8 floats

    const int rows = Bb * BLK_N;                         // 103424, divisible by 4
    lse_kernel<<<rows / 4, 256, 0, stream>>>(logits, targets, blankH, emitH);
    dp_kernel<<<Bb, 576, 0, stream>>>(blankH, emitH, logit_lengths, target_lengths, nll);
    mean_kernel<<<1, 64, 0, stream>>>(nll, out);
}